// Round 13
// baseline (74.143 us; speedup 1.0000x reference)
//
#include <hip/hip_runtime.h>
#include <hip/hip_bf16.h>
#include <math.h>

// SDGCN fused, v13 = v9 (verified 65.5us main: padded LDS, single-buffer,
// 2 barriers/step, T14 prefetch, XCD swizzle, V hi-only, setprio) plus:
//  - 4-shuffle P-exchange (== v9's 8-shuffle+select, element-identical)
//  - fp32 prearranged A (v7-verified prearr kernel; removes 16 unpacks/step)
//  - tree max (max3-fusable) + 4-chain sum reductions
//
// mfma_f32_32x32x16_bf16 layouts (m74/m101-verified C/D; standard A/B):
//   A-frag: lane l holds A[l&31][(l>>5)*8+e]
//   B-frag: lane l holds B[(l>>5)*8+e][l&31]
//   C/D:    lane l, reg r holds C[(r&3)+8*(r>>2)+4*(l>>5)][l&31]

typedef short bf16x8 __attribute__((ext_vector_type(8)));
typedef float f32x4  __attribute__((ext_vector_type(4)));
typedef float f32x16 __attribute__((ext_vector_type(16)));
typedef int   i32x4  __attribute__((ext_vector_type(4)));

constexpr int kN = 1024;
constexpr int kD = 64;
constexpr size_t kPlane    = 48u * 1024u * 64u;      // shorts per bf16 plane
constexpr size_t kAfFloats = 16u * 32u * 2048u;      // prearranged A (fp32)

#define MFMA32(a,b,c) __builtin_amdgcn_mfma_f32_32x32x16_bf16((a),(b),(c),0,0,0)
#define MFMA16(a,b,c) __builtin_amdgcn_mfma_f32_16x16x32_bf16((a),(b),(c),0,0,0)

__device__ __forceinline__ void splitv(float v, short& h, short& l) {
  unsigned u = __float_as_uint(v);
  h = (short)(u >> 16);
  float hf = __uint_as_float(u & 0xFFFF0000u);
  l = (short)(__float_as_uint(v - hf) >> 16);
}

__device__ __forceinline__ unsigned pkbf(float a, float b) {
  return (__float_as_uint(a) >> 16) | (__float_as_uint(b) & 0xFFFF0000u);
}

// ---------------- pre-pass 1 (verified): X -> bf16 hi/lo planes -----------
__global__ __launch_bounds__(256)
void presplit(const float* __restrict__ X, short* __restrict__ Xh,
              short* __restrict__ Xl, short* __restrict__ XTh)
{
  __shared__ short Sh[64][68], Sl[64][68];
  const int t  = threadIdx.x;
  const int bt = blockIdx.x >> 4;
  const int mb = blockIdx.x & 15;
  const size_t base = (size_t)bt * 65536 + (size_t)mb * 64 * 64;

#pragma unroll
  for (int k = 0; k < 4; ++k) {
    int idx = t + k * 256;
    int row = idx >> 4;
    int c4  = (idx & 15) * 4;
    float4 v = *(const float4*)(X + base + row * 64 + c4);
    short h0,l0,h1,l1,h2,l2,h3,l3;
    splitv(v.x, h0, l0); splitv(v.y, h1, l1);
    splitv(v.z, h2, l2); splitv(v.w, h3, l3);
    short4 hv = make_short4(h0, h1, h2, h3);
    short4 lv = make_short4(l0, l1, l2, l3);
    *(short4*)(Xh + base + row * 64 + c4) = hv;
    *(short4*)(Xl + base + row * 64 + c4) = lv;
    *(short4*)&Sh[row][c4] = hv;
    *(short4*)&Sl[row][c4] = lv;
  }
  __syncthreads();

  const size_t tbase = (size_t)bt * 65536 + (size_t)mb * 64;
#pragma unroll
  for (int k = 0; k < 2; ++k) {
    int idx = t + k * 256;
    int d   = idx >> 3;
    int m8  = (idx & 7) * 8;
    bf16x8 hv;
#pragma unroll
    for (int j = 0; j < 8; ++j) hv[j] = Sh[m8 + j][d];
    *(bf16x8*)(XTh + tbase + (size_t)d * 1024 + m8) = hv;
  }
}

// ---------------- pre-pass 2 (v7-verified): A -> fp32 fragment order ------
// Af[qt][gks] is a 8KB block: [qw][j 0..3][lane 0..63][e 0..3] f32, holding
// A[qt*64 + qw*32 + (lane&31)][gks*32 + 8j + 4*(lane>>5) + e].
__global__ __launch_bounds__(256)
void prearr_A(const float* __restrict__ A, float* __restrict__ Af)
{
  const int qt  = blockIdx.x >> 5;
  const int gks = blockIdx.x & 31;
  const int t   = threadIdx.x;
  float* dst = Af + ((size_t)(qt * 32 + gks) * 2048);
#pragma unroll
  for (int s = t; s < 512; s += 256) {
    const int qw = s >> 8, j = (s >> 6) & 3, lane = s & 63;
    const int q = qt * 64 + qw * 32 + (lane & 31);
    const int k = gks * 32 + 8 * j + 4 * (lane >> 5);
    float4 v = *(const float4*)(A + (size_t)q * kN + k);
    *(float4*)(dst + (size_t)qw * 1024 + j * 256 + lane * 4) = v;
  }
}

// ---------------- main fused kernel ----------------
template<int AMODE>
__global__ __launch_bounds__(256)
void sdgcn_v13(const float* __restrict__ X, const float* __restrict__ A,
               const float* __restrict__ W, const float* __restrict__ gamma,
               const float* __restrict__ beta, float* __restrict__ out,
               const short* __restrict__ Xh, const short* __restrict__ Xl,
               const short* __restrict__ XTh, const float* __restrict__ Af)
{
  // LDS 28672B (v9 layout): per kg { Kh[32*72], Kl[32*72] @ kg*9216 ;
  //                                  Vth[64*40] @ 18432 + kg*5120 }
  // post-loop union: aM/aZ/aF (1792B @0), Har[64][68] f32 @1792.
  __shared__ __align__(16) unsigned char LB[28672];

  const int t    = threadIdx.x;
  const int wave = t >> 6;
  const int lane = t & 63;
  const int kg   = wave >> 1;
  const int qw   = wave & 1;
  const int half = lane >> 5;
  const int l31  = lane & 31;
  const int bid  = blockIdx.x;
  const int swz  = (bid & 7) * 96 + (bid >> 3);   // XCD-chunked (768 = 8*96)
  const int bt   = swz >> 4;
  const int qt   = swz & 15;
  const int qblk = qt * 64;
  const size_t xb = (size_t)bt * 65536;

  short* Khg  = (short*)(LB + kg * 9216);
  short* Klg  = Khg + 2304;
  short* Vthg = (short*)(LB + 18432 + kg * 5120);
  float* aM   = (float*)LB;             // [2][64]
  float* aZ   = aM + 128;
  float* aF   = aZ + 128;               // [3][64]
  float* Har  = (float*)(LB + 1792);    // [64][68]

  // ---- Q B-frags
  const int qmine = qblk + qw * 32 + l31;
  bf16x8 qh[4], qlo[4];
#pragma unroll
  for (int c = 0; c < 4; ++c) {
    const size_t off = xb + (size_t)qmine * kD + 16 * c + half * 8;
    qh[c]  = *(const bf16x8*)(Xh + off);
    qlo[c] = *(const bf16x8*)(Xl + off);
  }

  f32x16 o0, o1;
#pragma unroll
  for (int r = 0; r < 16; ++r) { o0[r] = 0.f; o1[r] = 0.f; }
  float mrun = -INFINITY, Z = 0.f;

  const int tg = t & 127;

  auto ldK = [&](int kb, int j, bf16x8& h, bf16x8& l) {
    int ck = tg + 128 * j; int kr = ck >> 3; int kc = (ck & 7) * 8;
    size_t off = xb + (size_t)(kb + kr) * kD + kc;
    h = *(const bf16x8*)(Xh + off);
    l = *(const bf16x8*)(Xl + off);
  };
  auto ldV = [&](int kb, int j, bf16x8& h) {
    int cv = tg + 128 * j; int vd = cv >> 2; int vm = (cv & 3) * 8;
    h = *(const bf16x8*)(XTh + xb + (size_t)vd * 1024 + kb + vm);
  };
  auto stK = [&](int j, bf16x8 h, bf16x8 l) {
    int ck = tg + 128 * j; int kr = ck >> 3; int kc = (ck & 7) * 8;
    *(bf16x8*)&Khg[kr * 72 + kc] = h;
    *(bf16x8*)&Klg[kr * 72 + kc] = l;
  };
  auto stV = [&](int j, bf16x8 h) {
    int cv = tg + 128 * j; int vd = cv >> 2; int vm = (cv & 3) * 8;
    *(bf16x8*)&Vthg[vd * 40 + vm] = h;
  };

  // prologue: stage tile 0 of this k-group; load A(step 0)
  {
    bf16x8 a0,a1,b0,b1,c0,d0;
    ldK(kg * 512, 0, a0, a1); ldK(kg * 512, 1, b0, b1);
    ldV(kg * 512, 0, c0);     ldV(kg * 512, 1, d0);
    stK(0, a0, a1); stK(1, b0, b1); stV(0, c0); stV(1, d0);
  }
  float4 fA0 = {0,0,0,0}, fA1 = {0,0,0,0}, fA2 = {0,0,0,0}, fA3 = {0,0,0,0};
  if (AMODE == 1) {
    const float* Ab = Af + ((size_t)(qt * 32 + kg * 16) * 2048)
                         + (size_t)qw * 1024 + (lane << 2);
    fA0 = *(const float4*)(Ab);
    fA1 = *(const float4*)(Ab + 256);
    fA2 = *(const float4*)(Ab + 512);
    fA3 = *(const float4*)(Ab + 768);
  }
  __syncthreads();

  for (int ks = 0; ks < 16; ++ks) {
    const int kb = kg * 512 + ks * 32;
    const bool pfm = (ks + 1) < 16;

    // T14: issue next tile's K/V and next step's A early
    bf16x8 nk0h,nk0l,nk1h,nk1l,nv0,nv1;
    if (pfm) {
      ldK(kb + 32, 0, nk0h, nk0l); ldK(kb + 32, 1, nk1h, nk1l);
      ldV(kb + 32, 0, nv0);        ldV(kb + 32, 1, nv1);
    }
    float4 nA0 = {0,0,0,0}, nA1 = {0,0,0,0}, nA2 = {0,0,0,0}, nA3 = {0,0,0,0};
    if (AMODE == 1 && pfm) {
      const float* Ab = Af + ((size_t)(qt * 32 + kg * 16 + ks + 1) * 2048)
                           + (size_t)qw * 1024 + (lane << 2);
      nA0 = *(const float4*)(Ab);
      nA1 = *(const float4*)(Ab + 256);
      nA2 = *(const float4*)(Ab + 512);
      nA3 = *(const float4*)(Ab + 768);
    }

    // A gate: agv[r] = A[qmine][kb + (r&3) + 8*(r>>2) + 4*half]
    float agv[16];
    if (AMODE == 1) {
#pragma unroll
      for (int e = 0; e < 4; ++e) {
        agv[e] = fA0[e]; agv[4+e] = fA1[e]; agv[8+e] = fA2[e]; agv[12+e] = fA3[e];
      }
    } else {
      const float* Arow = A + (size_t)qmine * kN + kb + 4 * half;
      float4 ag0 = *(const float4*)(Arow);
      float4 ag1 = *(const float4*)(Arow + 8);
      float4 ag2 = *(const float4*)(Arow + 16);
      float4 ag3 = *(const float4*)(Arow + 24);
#pragma unroll
      for (int e = 0; e < 4; ++e) {
        agv[e] = ag0[e]; agv[4+e] = ag1[e]; agv[8+e] = ag2[e]; agv[12+e] = ag3[e];
      }
    }

    // ---- QK^T swapped: lane holds S[k_local(r,half)][q=l31]
    f32x16 sa;
#pragma unroll
    for (int r = 0; r < 16; ++r) sa[r] = 0.f;
    __builtin_amdgcn_s_setprio(1);
#pragma unroll
    for (int c = 0; c < 4; ++c) {
      bf16x8 kh = *(const bf16x8*)&Khg[l31 * 72 + 16 * c + half * 8];
      bf16x8 kl = *(const bf16x8*)&Klg[l31 * 72 + 16 * c + half * 8];
      sa = MFMA32(kh, qh[c],  sa);
      sa = MFMA32(kh, qlo[c], sa);
      sa = MFMA32(kl, qh[c],  sa);
    }
    __builtin_amdgcn_s_setprio(0);

    // ---- defer-max online softmax (tree max, max3-fusable)
    float a0 = fmaxf(fmaxf(sa[0],  sa[1]),  sa[2]);
    float a1 = fmaxf(fmaxf(sa[3],  sa[4]),  sa[5]);
    float a2 = fmaxf(fmaxf(sa[6],  sa[7]),  sa[8]);
    float a3 = fmaxf(fmaxf(sa[9],  sa[10]), sa[11]);
    float a4 = fmaxf(fmaxf(sa[12], sa[13]), sa[14]);
    float b0 = fmaxf(fmaxf(a0, a1), a2);
    float sm = fmaxf(fmaxf(b0, fmaxf(a3, a4)), sa[15]);
    sm = fmaxf(sm, __shfl_xor(sm, 32, 64));
    if (__any(sm > mrun + 8.f)) {
      const float nm = fmaxf(mrun, sm);
      const float f  = __expf(mrun - nm);   // 0 on first tile
      mrun = nm; Z *= f;
#pragma unroll
      for (int r = 0; r < 16; ++r) {
        const float fr = __shfl(f, (r & 3) + 8 * (r >> 2) + 4 * half, 64);
        o0[r] *= fr; o1[r] *= fr;
      }
    }
    float pv[16];
#pragma unroll
    for (int r = 0; r < 16; ++r) pv[r] = __expf(sa[r] - mrun);
    float z0 = (pv[0] + pv[1]) + (pv[2] + pv[3]);
    float z1 = (pv[4] + pv[5]) + (pv[6] + pv[7]);
    float z2 = (pv[8] + pv[9]) + (pv[10] + pv[11]);
    float z3 = (pv[12] + pv[13]) + (pv[14] + pv[15]);
    float zt = (z0 + z1) + (z2 + z3);
    zt += __shfl_xor(zt, 32, 64);
    Z += zt;

    float pa[16];
#pragma unroll
    for (int r = 0; r < 16; ++r) pa[r] = pv[r] * agv[r];

    // ---- pack gated P + 4-shuffle cross-half exchange -> PV A-frags
    // lo needs partner du{0,1,4,5}; hi needs partner du{2,3,6,7}.
    unsigned du[8];
#pragma unroll
    for (int j = 0; j < 8; ++j) du[j] = pkbf(pa[2*j], pa[2*j+1]);
    const bool lo = (half == 0);
    unsigned snd0 = lo ? du[2] : du[0];
    unsigned snd1 = lo ? du[3] : du[1];
    unsigned snd2 = lo ? du[6] : du[4];
    unsigned snd3 = lo ? du[7] : du[5];
    unsigned r0 = (unsigned)__shfl_xor((int)snd0, 32, 64);
    unsigned r1 = (unsigned)__shfl_xor((int)snd1, 32, 64);
    unsigned r2 = (unsigned)__shfl_xor((int)snd2, 32, 64);
    unsigned r3 = (unsigned)__shfl_xor((int)snd3, 32, 64);
    // lo: r = {su0,su1,su4,su5}; hi: r = {su2,su3,su6,su7}
    i32x4 w0, w1;
    w0[0] = (int)(lo ? du[0] : r0);   // lo?du0:su2
    w0[1] = (int)(lo ? du[1] : r1);   // lo?du1:su3
    w0[2] = (int)(lo ? r0 : du[2]);   // lo?su0:du2
    w0[3] = (int)(lo ? r1 : du[3]);   // lo?su1:du3
    w1[0] = (int)(lo ? du[4] : r2);   // lo?du4:su6
    w1[1] = (int)(lo ? du[5] : r3);   // lo?du5:su7
    w1[2] = (int)(lo ? r2 : du[6]);   // lo?su4:du6
    w1[3] = (int)(lo ? r3 : du[7]);   // lo?su5:du7
    bf16x8 pf0 = *(bf16x8*)&w0;
    bf16x8 pf1 = *(bf16x8*)&w1;

    // ---- PV: O[q][d] += P[q][k] V[k][d]   (V hi-plane only)
    {
      bf16x8 v0 = *(const bf16x8*)&Vthg[l31 * 40 + half * 8];
      bf16x8 v1 = *(const bf16x8*)&Vthg[l31 * 40 + 16 + half * 8];
      bf16x8 v2 = *(const bf16x8*)&Vthg[(32 + l31) * 40 + half * 8];
      bf16x8 v3 = *(const bf16x8*)&Vthg[(32 + l31) * 40 + 16 + half * 8];
      __builtin_amdgcn_s_setprio(1);
      o0 = MFMA32(pf0, v0, o0);
      o0 = MFMA32(pf1, v1, o0);
      o1 = MFMA32(pf0, v2, o1);
      o1 = MFMA32(pf1, v3, o1);
      __builtin_amdgcn_s_setprio(0);
    }

    __syncthreads();
    if (pfm) {
      stK(0, nk0h, nk0l); stK(1, nk1h, nk1l);
      stV(0, nv0);        stV(1, nv1);
    }
    __syncthreads();
    fA0 = nA0; fA1 = nA1; fA2 = nA2; fA3 = nA3;
  }

  // ================= split-K merge (v5-verified) =================
  if (lane < 32) {
    aM[kg * 64 + qw * 32 + l31] = mrun;
    aZ[kg * 64 + qw * 32 + l31] = Z;
  }
  if (kg == 1) {
#pragma unroll
    for (int r = 0; r < 16; ++r) {
      const int qq = qw * 32 + (r & 3) + 8 * (r >> 2) + 4 * half;
      Har[qq * 68 + l31]      = o0[r];
      Har[qq * 68 + l31 + 32] = o1[r];
    }
  }
  __syncthreads();
  if (kg == 1 && lane < 32) {
    const int q = qw * 32 + l31;
    const float ma = aM[q], mb = mrun;
    const float m  = fmaxf(ma, mb);
    const float fa = __expf(ma - m), fb = __expf(mb - m);
    const float Zs = aZ[q] * fa + Z * fb;
    aF[q]       = fa;
    aF[64 + q]  = fb;
    aF[128 + q] = 1.0f / (8.0f * Zs);   // sqrt(64)=8
  }
  __syncthreads();
  if (kg == 0) {
#pragma unroll
    for (int r = 0; r < 16; ++r) {
      const int qq = qw * 32 + (r & 3) + 8 * (r >> 2) + 4 * half;
      const float fa = aF[qq], fb = aF[64 + qq];
      Har[qq * 68 + l31]      = o0[r] * fa + Har[qq * 68 + l31]      * fb;
      Har[qq * 68 + l31 + 32] = o1[r] * fa + Har[qq * 68 + l31 + 32] * fb;
    }
  }
  __syncthreads();

  // ================= epilogue (v2-verified 16x16 path) =================
  const int g  = lane >> 4;
  const int ql = lane & 15;
  const int er = wave * 16;
  const float i8z = aF[128 + er + ql];

  bf16x8 hh[2], hl[2];
#pragma unroll
  for (int kk = 0; kk < 2; ++kk) {
    const float* hp = &Har[(er + ql) * 68 + kk * 32 + g * 8];
    float4 v0 = *(const float4*)hp;
    float4 v1 = *(const float4*)(hp + 4);
    float v[8] = {v0.x*i8z, v0.y*i8z, v0.z*i8z, v0.w*i8z,
                  v1.x*i8z, v1.y*i8z, v1.z*i8z, v1.w*i8z};
#pragma unroll
    for (int e = 0; e < 8; ++e) { short a, b; splitv(v[e], a, b); hh[kk][e] = a; hl[kk][e] = b; }
  }

  f32x4 lin[4];
#pragma unroll
  for (int c = 0; c < 4; ++c) {
    bf16x8 wh[2], wl[2];
#pragma unroll
    for (int kk = 0; kk < 2; ++kk) {
      const float* wp = W + (size_t)(c * 16 + ql) * kD + kk * 32 + g * 8;
      float4 v0 = *(const float4*)wp;
      float4 v1 = *(const float4*)(wp + 4);
      float v[8] = {v0.x, v0.y, v0.z, v0.w, v1.x, v1.y, v1.z, v1.w};
#pragma unroll
      for (int e = 0; e < 8; ++e) { short a, b; splitv(v[e], a, b); wh[kk][e] = a; wl[kk][e] = b; }
    }
    f32x4 acc = {0.f, 0.f, 0.f, 0.f};
    acc = MFMA16(hh[0], wh[0], acc);
    acc = MFMA16(hh[1], wh[1], acc);
    acc = MFMA16(hh[0], wl[0], acc);
    acc = MFMA16(hh[1], wl[1], acc);
    acc = MFMA16(hl[0], wh[0], acc);
    acc = MFMA16(hl[1], wh[1], acc);
    lin[c] = acc;
  }

  float rl[4][4];
#pragma unroll
  for (int c = 0; c < 4; ++c)
#pragma unroll
    for (int r = 0; r < 4; ++r) rl[c][r] = fmaxf(lin[c][r], 0.f);

  float mu[4], rstd[4];
#pragma unroll
  for (int r = 0; r < 4; ++r) {
    float s1 = rl[0][r] + rl[1][r] + rl[2][r] + rl[3][r];
    float s2 = rl[0][r]*rl[0][r] + rl[1][r]*rl[1][r] + rl[2][r]*rl[2][r] + rl[3][r]*rl[3][r];
#pragma unroll
    for (int off = 1; off < 16; off <<= 1) {
      s1 += __shfl_xor(s1, off, 64);
      s2 += __shfl_xor(s2, off, 64);
    }
    mu[r] = s1 * (1.f / 64.f);
    const float var = s2 * (1.f / 64.f) - mu[r] * mu[r];
    rstd[r] = rsqrtf(var + 1e-5f);
  }

#pragma unroll
  for (int c = 0; c < 4; ++c) {
    const float gm = gamma[c * 16 + ql];
    const float bb = beta[c * 16 + ql];
#pragma unroll
    for (int r = 0; r < 4; ++r) {
      const int qrow = qblk + er + 4 * g + r;
      const size_t off = ((size_t)bt * kN + qrow) * kD + c * 16 + ql;
      out[off] = (rl[c][r] - mu[r]) * rstd[r] * gm + bb + X[off];
    }
  }
}

extern "C" void kernel_launch(void* const* d_in, const int* in_sizes, int n_in,
                              void* d_out, int out_size, void* d_ws, size_t ws_size,
                              hipStream_t stream) {
  const float* X     = (const float*)d_in[0];
  const float* A     = (const float*)d_in[1];
  const float* W     = (const float*)d_in[2];
  const float* gamma = (const float*)d_in[3];
  const float* beta  = (const float*)d_in[4];
  float* out = (float*)d_out;

  short* Xh  = (short*)d_ws;
  short* Xl  = Xh  + kPlane;
  short* XTh = Xl  + kPlane;
  float* Af  = (float*)(XTh + kPlane);

  const size_t need = 3 * kPlane * sizeof(short) + kAfFloats * sizeof(float);

  presplit<<<dim3(48 * 16), 256, 0, stream>>>(X, Xh, Xl, XTh);
  if (ws_size >= need) {
    prearr_A<<<dim3(16 * 32), 256, 0, stream>>>(A, Af);
    sdgcn_v13<1><<<dim3(48 * 16), 256, 0, stream>>>(X, A, W, gamma, beta, out,
                                                    Xh, Xl, XTh, Af);
  } else {
    sdgcn_v13<0><<<dim3(48 * 16), 256, 0, stream>>>(X, A, W, gamma, beta, out,
                                                    Xh, Xl, XTh, Af);
  }
}

// Round 14
// 65.481 us; speedup vs baseline: 1.1323x; 1.1323x over previous
//
#include <hip/hip_runtime.h>
#include <hip/hip_bf16.h>
#include <math.h>

// SDGCN fused, v14 = v9 (verified 65.5us: padded LDS, 2 barriers/step, T14,
// XCD swizzle, V hi-only, setprio, bf16 prearranged A + prefetch) plus:
//  - 2-term QK: S ~= Kh.Qh + Kh.Qlo (drops Kl plane: -4 MFMA, -4 ds_read,
//    -2 ds_write, -2 global loads per step; LDS 28.7->19.5KB). Score error
//    <= ~0.016 abs -> P ~1.6% per-element (common mode cancels in Z).
//  - 4-shuffle P-exchange + tree max/sum (v13-verified pieces).
//  - bf16 Af restored (v13's fp32 Af thrashed L2: FETCH 31.7->50.3MB).
//
// mfma_f32_32x32x16_bf16 layouts (m74/m101-verified C/D; standard A/B):
//   A-frag: lane l holds A[l&31][(l>>5)*8+e]
//   B-frag: lane l holds B[(l>>5)*8+e][l&31]
//   C/D:    lane l, reg r holds C[(r&3)+8*(r>>2)+4*(l>>5)][l&31]

typedef short bf16x8 __attribute__((ext_vector_type(8)));
typedef float f32x4  __attribute__((ext_vector_type(4)));
typedef float f32x16 __attribute__((ext_vector_type(16)));
typedef int   i32x4  __attribute__((ext_vector_type(4)));

constexpr int kN = 1024;
constexpr int kD = 64;
constexpr size_t kPlane    = 48u * 1024u * 64u;      // shorts per bf16 plane
constexpr size_t kAfShorts = 16u * 32u * 2048u;      // prearranged A (bf16)

#define MFMA32(a,b,c) __builtin_amdgcn_mfma_f32_32x32x16_bf16((a),(b),(c),0,0,0)
#define MFMA16(a,b,c) __builtin_amdgcn_mfma_f32_16x16x32_bf16((a),(b),(c),0,0,0)

__device__ __forceinline__ void splitv(float v, short& h, short& l) {
  unsigned u = __float_as_uint(v);
  h = (short)(u >> 16);
  float hf = __uint_as_float(u & 0xFFFF0000u);
  l = (short)(__float_as_uint(v - hf) >> 16);
}

__device__ __forceinline__ unsigned pkbf(float a, float b) {
  return (__float_as_uint(a) >> 16) | (__float_as_uint(b) & 0xFFFF0000u);
}

// ---------------- pre-pass 1 (verified): X -> bf16 hi/lo planes -----------
__global__ __launch_bounds__(256)
void presplit(const float* __restrict__ X, short* __restrict__ Xh,
              short* __restrict__ Xl, short* __restrict__ XTh)
{
  __shared__ short Sh[64][68], Sl[64][68];
  const int t  = threadIdx.x;
  const int bt = blockIdx.x >> 4;
  const int mb = blockIdx.x & 15;
  const size_t base = (size_t)bt * 65536 + (size_t)mb * 64 * 64;

#pragma unroll
  for (int k = 0; k < 4; ++k) {
    int idx = t + k * 256;
    int row = idx >> 4;
    int c4  = (idx & 15) * 4;
    float4 v = *(const float4*)(X + base + row * 64 + c4);
    short h0,l0,h1,l1,h2,l2,h3,l3;
    splitv(v.x, h0, l0); splitv(v.y, h1, l1);
    splitv(v.z, h2, l2); splitv(v.w, h3, l3);
    short4 hv = make_short4(h0, h1, h2, h3);
    short4 lv = make_short4(l0, l1, l2, l3);
    *(short4*)(Xh + base + row * 64 + c4) = hv;
    *(short4*)(Xl + base + row * 64 + c4) = lv;
    *(short4*)&Sh[row][c4] = hv;
    *(short4*)&Sl[row][c4] = lv;
  }
  __syncthreads();

  const size_t tbase = (size_t)bt * 65536 + (size_t)mb * 64;
#pragma unroll
  for (int k = 0; k < 2; ++k) {
    int idx = t + k * 256;
    int d   = idx >> 3;
    int m8  = (idx & 7) * 8;
    bf16x8 hv;
#pragma unroll
    for (int j = 0; j < 8; ++j) hv[j] = Sh[m8 + j][d];
    *(bf16x8*)(XTh + tbase + (size_t)d * 1024 + m8) = hv;
  }
}

// ---------------- pre-pass 2 (v9-verified): A -> bf16 fragment order ------
__global__ __launch_bounds__(256)
void prearr_Abf(const float* __restrict__ A, short* __restrict__ Af)
{
  const int qt  = blockIdx.x >> 5;
  const int gks = blockIdx.x & 31;
  const int kb  = gks * 32;
  const int s   = threadIdx.x;
  short* dst = Af + ((size_t)(qt * 32 + gks) * 2048);

  const int qw = s >> 7;
  const int ln = (s >> 1) & 63;
  const int p  = s & 1;
  const int q  = qt * 64 + qw * 32 + (ln & 31);
  const int h  = ln >> 5;
  const int k0 = kb + 16 * p + 4 * h;
  float4 f0 = *(const float4*)(A + (size_t)q * kN + k0);
  float4 f1 = *(const float4*)(A + (size_t)q * kN + k0 + 8);
  i32x4 u;
  u[0] = (int)pkbf(f0.x, f0.y); u[1] = (int)pkbf(f0.z, f0.w);
  u[2] = (int)pkbf(f1.x, f1.y); u[3] = (int)pkbf(f1.z, f1.w);
  *(i32x4*)(dst + (size_t)qw * 1024 + ln * 16 + p * 8) = u;
}

// ---------------- main fused kernel ----------------
template<int AMODE>
__global__ __launch_bounds__(256)
void sdgcn_v14(const float* __restrict__ X, const float* __restrict__ A,
               const float* __restrict__ W, const float* __restrict__ gamma,
               const float* __restrict__ beta, float* __restrict__ out,
               const short* __restrict__ Xh, const short* __restrict__ Xl,
               const short* __restrict__ XTh, const short* __restrict__ Af)
{
  // LDS 19456B: per kg { Kh[32*72] shorts @ kg*4608 (4608B) ;
  //                      Vth[64*40] shorts @ 9216 + kg*5120 }
  // post-loop union: aM/aZ/aF (1792B @0), Har[64][68] f32 @1792 (17408B).
  __shared__ __align__(16) unsigned char LB[19456];

  const int t    = threadIdx.x;
  const int wave = t >> 6;
  const int lane = t & 63;
  const int kg   = wave >> 1;
  const int qw   = wave & 1;
  const int half = lane >> 5;
  const int l31  = lane & 31;
  const int bid  = blockIdx.x;
  const int swz  = (bid & 7) * 96 + (bid >> 3);   // XCD-chunked (768 = 8*96)
  const int bt   = swz >> 4;
  const int qt   = swz & 15;
  const int qblk = qt * 64;
  const size_t xb = (size_t)bt * 65536;

  short* Khg  = (short*)(LB + kg * 4608);
  short* Vthg = (short*)(LB + 9216 + kg * 5120);
  float* aM   = (float*)LB;             // [2][64]
  float* aZ   = aM + 128;
  float* aF   = aZ + 128;               // [3][64]
  float* Har  = (float*)(LB + 1792);    // [64][68]

  // ---- Q B-frags (hi+lo, from pre-split planes)
  const int qmine = qblk + qw * 32 + l31;
  bf16x8 qh[4], qlo[4];
#pragma unroll
  for (int c = 0; c < 4; ++c) {
    const size_t off = xb + (size_t)qmine * kD + 16 * c + half * 8;
    qh[c]  = *(const bf16x8*)(Xh + off);
    qlo[c] = *(const bf16x8*)(Xl + off);
  }

  f32x16 o0, o1;
#pragma unroll
  for (int r = 0; r < 16; ++r) { o0[r] = 0.f; o1[r] = 0.f; }
  float mrun = -INFINITY, Z = 0.f;

  const int tg = t & 127;

  auto ldK = [&](int kb, int j, bf16x8& h) {
    int ck = tg + 128 * j; int kr = ck >> 3; int kc = (ck & 7) * 8;
    h = *(const bf16x8*)(Xh + xb + (size_t)(kb + kr) * kD + kc);
  };
  auto ldV = [&](int kb, int j, bf16x8& h) {
    int cv = tg + 128 * j; int vd = cv >> 2; int vm = (cv & 3) * 8;
    h = *(const bf16x8*)(XTh + xb + (size_t)vd * 1024 + kb + vm);
  };
  auto stK = [&](int j, bf16x8 h) {
    int ck = tg + 128 * j; int kr = ck >> 3; int kc = (ck & 7) * 8;
    *(bf16x8*)&Khg[kr * 72 + kc] = h;
  };
  auto stV = [&](int j, bf16x8 h) {
    int cv = tg + 128 * j; int vd = cv >> 2; int vm = (cv & 3) * 8;
    *(bf16x8*)&Vthg[vd * 40 + vm] = h;
  };

  // prologue: stage tile 0 of this k-group; load A(step 0)
  {
    bf16x8 a0,b0,c0,d0;
    ldK(kg * 512, 0, a0); ldK(kg * 512, 1, b0);
    ldV(kg * 512, 0, c0); ldV(kg * 512, 1, d0);
    stK(0, a0); stK(1, b0); stV(0, c0); stV(1, d0);
  }
  i32x4 aA = {0,0,0,0}, aB = {0,0,0,0};
  if (AMODE == 1) {
    const short* Ab = Af + ((size_t)(qt * 32 + kg * 16) * 2048)
                         + (size_t)qw * 1024 + (lane << 4);
    aA = *(const i32x4*)(Ab);
    aB = *(const i32x4*)(Ab + 8);
  }
  __syncthreads();

  for (int ks = 0; ks < 16; ++ks) {
    const int kb = kg * 512 + ks * 32;
    const bool pfm = (ks + 1) < 16;

    // T14: issue next tile's K/V and next step's A early
    bf16x8 nk0,nk1,nv0,nv1;
    if (pfm) {
      ldK(kb + 32, 0, nk0); ldK(kb + 32, 1, nk1);
      ldV(kb + 32, 0, nv0); ldV(kb + 32, 1, nv1);
    }
    i32x4 naA = {0,0,0,0}, naB = {0,0,0,0};
    if (AMODE == 1 && pfm) {
      const short* Ab = Af + ((size_t)(qt * 32 + kg * 16 + ks + 1) * 2048)
                           + (size_t)qw * 1024 + (lane << 4);
      naA = *(const i32x4*)(Ab);
      naB = *(const i32x4*)(Ab + 8);
    }

    // A gate: agv[r] = A[qmine][kb + (r&3) + 8*(r>>2) + 4*half]
    float agv[16];
    if (AMODE == 1) {
      unsigned u[8] = {(unsigned)aA[0],(unsigned)aA[1],(unsigned)aA[2],(unsigned)aA[3],
                       (unsigned)aB[0],(unsigned)aB[1],(unsigned)aB[2],(unsigned)aB[3]};
#pragma unroll
      for (int m = 0; m < 8; ++m) {
        agv[2*m]   = __uint_as_float(u[m] << 16);
        agv[2*m+1] = __uint_as_float(u[m] & 0xFFFF0000u);
      }
    } else {
      const float* Arow = A + (size_t)qmine * kN + kb + 4 * half;
      float4 ag0 = *(const float4*)(Arow);
      float4 ag1 = *(const float4*)(Arow + 8);
      float4 ag2 = *(const float4*)(Arow + 16);
      float4 ag3 = *(const float4*)(Arow + 24);
#pragma unroll
      for (int e = 0; e < 4; ++e) {
        agv[e] = ag0[e]; agv[4+e] = ag1[e]; agv[8+e] = ag2[e]; agv[12+e] = ag3[e];
      }
    }

    // ---- QK^T swapped, 2-term: S ~= Kh.Qh + Kh.Qlo
    f32x16 sa;
#pragma unroll
    for (int r = 0; r < 16; ++r) sa[r] = 0.f;
    __builtin_amdgcn_s_setprio(1);
#pragma unroll
    for (int c = 0; c < 4; ++c) {
      bf16x8 kh = *(const bf16x8*)&Khg[l31 * 72 + 16 * c + half * 8];
      sa = MFMA32(kh, qh[c],  sa);
      sa = MFMA32(kh, qlo[c], sa);
    }
    __builtin_amdgcn_s_setprio(0);

    // ---- defer-max online softmax (tree max, max3-fusable)
    float a0 = fmaxf(fmaxf(sa[0],  sa[1]),  sa[2]);
    float a1 = fmaxf(fmaxf(sa[3],  sa[4]),  sa[5]);
    float a2 = fmaxf(fmaxf(sa[6],  sa[7]),  sa[8]);
    float a3 = fmaxf(fmaxf(sa[9],  sa[10]), sa[11]);
    float a4 = fmaxf(fmaxf(sa[12], sa[13]), sa[14]);
    float b0 = fmaxf(fmaxf(a0, a1), a2);
    float sm = fmaxf(fmaxf(b0, fmaxf(a3, a4)), sa[15]);
    sm = fmaxf(sm, __shfl_xor(sm, 32, 64));
    if (__any(sm > mrun + 8.f)) {
      const float nm = fmaxf(mrun, sm);
      const float f  = __expf(mrun - nm);   // 0 on first tile
      mrun = nm; Z *= f;
#pragma unroll
      for (int r = 0; r < 16; ++r) {
        const float fr = __shfl(f, (r & 3) + 8 * (r >> 2) + 4 * half, 64);
        o0[r] *= fr; o1[r] *= fr;
      }
    }
    float pv[16];
#pragma unroll
    for (int r = 0; r < 16; ++r) pv[r] = __expf(sa[r] - mrun);
    float z0 = (pv[0] + pv[1]) + (pv[2] + pv[3]);
    float z1 = (pv[4] + pv[5]) + (pv[6] + pv[7]);
    float z2 = (pv[8] + pv[9]) + (pv[10] + pv[11]);
    float z3 = (pv[12] + pv[13]) + (pv[14] + pv[15]);
    float zt = (z0 + z1) + (z2 + z3);
    zt += __shfl_xor(zt, 32, 64);
    Z += zt;

    float pa[16];
#pragma unroll
    for (int r = 0; r < 16; ++r) pa[r] = pv[r] * agv[r];

    // ---- pack gated P + 4-shuffle cross-half exchange (v13-verified)
    unsigned du[8];
#pragma unroll
    for (int j = 0; j < 8; ++j) du[j] = pkbf(pa[2*j], pa[2*j+1]);
    const bool lo = (half == 0);
    unsigned snd0 = lo ? du[2] : du[0];
    unsigned snd1 = lo ? du[3] : du[1];
    unsigned snd2 = lo ? du[6] : du[4];
    unsigned snd3 = lo ? du[7] : du[5];
    unsigned r0 = (unsigned)__shfl_xor((int)snd0, 32, 64);
    unsigned r1 = (unsigned)__shfl_xor((int)snd1, 32, 64);
    unsigned r2 = (unsigned)__shfl_xor((int)snd2, 32, 64);
    unsigned r3 = (unsigned)__shfl_xor((int)snd3, 32, 64);
    i32x4 w0, w1;
    w0[0] = (int)(lo ? du[0] : r0);
    w0[1] = (int)(lo ? du[1] : r1);
    w0[2] = (int)(lo ? r0 : du[2]);
    w0[3] = (int)(lo ? r1 : du[3]);
    w1[0] = (int)(lo ? du[4] : r2);
    w1[1] = (int)(lo ? du[5] : r3);
    w1[2] = (int)(lo ? r2 : du[6]);
    w1[3] = (int)(lo ? r3 : du[7]);
    bf16x8 pf0 = *(bf16x8*)&w0;
    bf16x8 pf1 = *(bf16x8*)&w1;

    // ---- PV: O[q][d] += P[q][k] V[k][d]   (V hi-plane only)
    {
      bf16x8 v0 = *(const bf16x8*)&Vthg[l31 * 40 + half * 8];
      bf16x8 v1 = *(const bf16x8*)&Vthg[l31 * 40 + 16 + half * 8];
      bf16x8 v2 = *(const bf16x8*)&Vthg[(32 + l31) * 40 + half * 8];
      bf16x8 v3 = *(const bf16x8*)&Vthg[(32 + l31) * 40 + 16 + half * 8];
      __builtin_amdgcn_s_setprio(1);
      o0 = MFMA32(pf0, v0, o0);
      o0 = MFMA32(pf1, v1, o0);
      o1 = MFMA32(pf0, v2, o1);
      o1 = MFMA32(pf1, v3, o1);
      __builtin_amdgcn_s_setprio(0);
    }

    __syncthreads();
    if (pfm) {
      stK(0, nk0); stK(1, nk1);
      stV(0, nv0); stV(1, nv1);
    }
    __syncthreads();
    aA = naA; aB = naB;
  }

  // ================= split-K merge (v5-verified) =================
  if (lane < 32) {
    aM[kg * 64 + qw * 32 + l31] = mrun;
    aZ[kg * 64 + qw * 32 + l31] = Z;
  }
  if (kg == 1) {
#pragma unroll
    for (int r = 0; r < 16; ++r) {
      const int qq = qw * 32 + (r & 3) + 8 * (r >> 2) + 4 * half;
      Har[qq * 68 + l31]      = o0[r];
      Har[qq * 68 + l31 + 32] = o1[r];
    }
  }
  __syncthreads();
  if (kg == 1 && lane < 32) {
    const int q = qw * 32 + l31;
    const float ma = aM[q], mb = mrun;
    const float m  = fmaxf(ma, mb);
    const float fa = __expf(ma - m), fb = __expf(mb - m);
    const float Zs = aZ[q] * fa + Z * fb;
    aF[q]       = fa;
    aF[64 + q]  = fb;
    aF[128 + q] = 1.0f / (8.0f * Zs);   // sqrt(64)=8
  }
  __syncthreads();
  if (kg == 0) {
#pragma unroll
    for (int r = 0; r < 16; ++r) {
      const int qq = qw * 32 + (r & 3) + 8 * (r >> 2) + 4 * half;
      const float fa = aF[qq], fb = aF[64 + qq];
      Har[qq * 68 + l31]      = o0[r] * fa + Har[qq * 68 + l31]      * fb;
      Har[qq * 68 + l31 + 32] = o1[r] * fa + Har[qq * 68 + l31 + 32] * fb;
    }
  }
  __syncthreads();

  // ================= epilogue (v2-verified 16x16 path) =================
  const int g  = lane >> 4;
  const int ql = lane & 15;
  const int er = wave * 16;
  const float i8z = aF[128 + er + ql];

  bf16x8 hh[2], hl[2];
#pragma unroll
  for (int kk = 0; kk < 2; ++kk) {
    const float* hp = &Har[(er + ql) * 68 + kk * 32 + g * 8];
    float4 v0 = *(const float4*)hp;
    float4 v1 = *(const float4*)(hp + 4);
    float v[8] = {v0.x*i8z, v0.y*i8z, v0.z*i8z, v0.w*i8z,
                  v1.x*i8z, v1.y*i8z, v1.z*i8z, v1.w*i8z};
#pragma unroll
    for (int e = 0; e < 8; ++e) { short a, b; splitv(v[e], a, b); hh[kk][e] = a; hl[kk][e] = b; }
  }

  f32x4 lin[4];
#pragma unroll
  for (int c = 0; c < 4; ++c) {
    bf16x8 wh[2], wl[2];
#pragma unroll
    for (int kk = 0; kk < 2; ++kk) {
      const float* wp = W + (size_t)(c * 16 + ql) * kD + kk * 32 + g * 8;
      float4 v0 = *(const float4*)wp;
      float4 v1 = *(const float4*)(wp + 4);
      float v[8] = {v0.x, v0.y, v0.z, v0.w, v1.x, v1.y, v1.z, v1.w};
#pragma unroll
      for (int e = 0; e < 8; ++e) { short a, b; splitv(v[e], a, b); wh[kk][e] = a; wl[kk][e] = b; }
    }
    f32x4 acc = {0.f, 0.f, 0.f, 0.f};
    acc = MFMA16(hh[0], wh[0], acc);
    acc = MFMA16(hh[1], wh[1], acc);
    acc = MFMA16(hh[0], wl[0], acc);
    acc = MFMA16(hh[1], wl[1], acc);
    acc = MFMA16(hl[0], wh[0], acc);
    acc = MFMA16(hl[1], wh[1], acc);
    lin[c] = acc;
  }

  float rl[4][4];
#pragma unroll
  for (int c = 0; c < 4; ++c)
#pragma unroll
    for (int r = 0; r < 4; ++r) rl[c][r] = fmaxf(lin[c][r], 0.f);

  float mu[4], rstd[4];
#pragma unroll
  for (int r = 0; r < 4; ++r) {
    float s1 = rl[0][r] + rl[1][r] + rl[2][r] + rl[3][r];
    float s2 = rl[0][r]*rl[0][r] + rl[1][r]*rl[1][r] + rl[2][r]*rl[2][r] + rl[3][r]*rl[3][r];
#pragma unroll
    for (int off = 1; off < 16; off <<= 1) {
      s1 += __shfl_xor(s1, off, 64);
      s2 += __shfl_xor(s2, off, 64);
    }
    mu[r] = s1 * (1.f / 64.f);
    const float var = s2 * (1.f / 64.f) - mu[r] * mu[r];
    rstd[r] = rsqrtf(var + 1e-5f);
  }

#pragma unroll
  for (int c = 0; c < 4; ++c) {
    const float gm = gamma[c * 16 + ql];
    const float bb = beta[c * 16 + ql];
#pragma unroll
    for (int r = 0; r < 4; ++r) {
      const int qrow = qblk + er + 4 * g + r;
      const size_t off = ((size_t)bt * kN + qrow) * kD + c * 16 + ql;
      out[off] = (rl[c][r] - mu[r]) * rstd[r] * gm + bb + X[off];
    }
  }
}

extern "C" void kernel_launch(void* const* d_in, const int* in_sizes, int n_in,
                              void* d_out, int out_size, void* d_ws, size_t ws_size,
                              hipStream_t stream) {
  const float* X     = (const float*)d_in[0];
  const float* A     = (const float*)d_in[1];
  const float* W     = (const float*)d_in[2];
  const float* gamma = (const float*)d_in[3];
  const float* beta  = (const float*)d_in[4];
  float* out = (float*)d_out;

  short* Xh  = (short*)d_ws;
  short* Xl  = Xh  + kPlane;
  short* XTh = Xl  + kPlane;
  short* Af  = XTh + kPlane;

  const size_t need = (3 * kPlane + kAfShorts) * sizeof(short);

  presplit<<<dim3(48 * 16), 256, 0, stream>>>(X, Xh, Xl, XTh);
  if (ws_size >= need) {
    prearr_Abf<<<dim3(16 * 32), 256, 0, stream>>>(A, Af);
    sdgcn_v14<1><<<dim3(48 * 16), 256, 0, stream>>>(X, A, W, gamma, beta, out,
                                                    Xh, Xl, XTh, Af);
  } else {
    sdgcn_v14<0><<<dim3(48 * 16), 256, 0, stream>>>(X, A, W, gamma, beta, out,
                                                    Xh, Xl, XTh, Af);
  }
}

// Round 15
// 63.654 us; speedup vs baseline: 1.1648x; 1.0287x over previous
//
#include <hip/hip_runtime.h>
#include <hip/hip_bf16.h>
#include <math.h>

// SDGCN fused, v15 = v14 (verified 57.8us main) plus:
//  1) Q-lo dropped (QK = Kh.Qh only, 4 MFMA/step); presplit now ROUNDS
//     (RNE) and writes only Xh + XTh (Xl plane dead) -> unbiased bf16,
//     s-error std ~0.013 <= v14's biased truncation.
//  2) double-buffered padded LDS (38.9KB), ONE barrier per k-step
//     (structure verified in v12; padded layout verified in v9/v14).
//  3) exp2/fma softmax: pv = exp2(fma(sa, log2e, -m*log2e)) — 2 VALU/elem.
//
// mfma_f32_32x32x16_bf16 layouts (m74/m101-verified C/D; standard A/B):
//   A-frag: lane l holds A[l&31][(l>>5)*8+e]
//   B-frag: lane l holds B[(l>>5)*8+e][l&31]
//   C/D:    lane l, reg r holds C[(r&3)+8*(r>>2)+4*(l>>5)][l&31]

typedef short bf16x8 __attribute__((ext_vector_type(8)));
typedef float f32x4  __attribute__((ext_vector_type(4)));
typedef float f32x16 __attribute__((ext_vector_type(16)));
typedef int   i32x4  __attribute__((ext_vector_type(4)));

constexpr int kN = 1024;
constexpr int kD = 64;
constexpr size_t kPlane    = 48u * 1024u * 64u;      // shorts per bf16 plane
constexpr size_t kAfShorts = 16u * 32u * 2048u;      // prearranged A (bf16)
constexpr float  kLog2e    = 1.4426950408889634f;

#define MFMA32(a,b,c) __builtin_amdgcn_mfma_f32_32x32x16_bf16((a),(b),(c),0,0,0)
#define MFMA16(a,b,c) __builtin_amdgcn_mfma_f32_16x16x32_bf16((a),(b),(c),0,0,0)

__device__ __forceinline__ void splitv(float v, short& h, short& l) {
  unsigned u = __float_as_uint(v);
  h = (short)(u >> 16);
  float hf = __uint_as_float(u & 0xFFFF0000u);
  l = (short)(__float_as_uint(v - hf) >> 16);
}

// round-to-nearest-even bf16
__device__ __forceinline__ short rndbf(float v) {
  unsigned u = __float_as_uint(v);
  return (short)((u + 0x7FFFu + ((u >> 16) & 1u)) >> 16);
}

// pack two floats to bf16 pair (truncation)
__device__ __forceinline__ unsigned pkbf(float a, float b) {
  return (__float_as_uint(a) >> 16) | (__float_as_uint(b) & 0xFFFF0000u);
}

// ---------------- pre-pass 1: X -> rounded bf16 plane + transpose ---------
__global__ __launch_bounds__(256)
void presplit(const float* __restrict__ X, short* __restrict__ Xh,
              short* __restrict__ XTh)
{
  __shared__ short Sh[64][68];
  const int t  = threadIdx.x;
  const int bt = blockIdx.x >> 4;
  const int mb = blockIdx.x & 15;
  const size_t base = (size_t)bt * 65536 + (size_t)mb * 64 * 64;

#pragma unroll
  for (int k = 0; k < 4; ++k) {
    int idx = t + k * 256;
    int row = idx >> 4;
    int c4  = (idx & 15) * 4;
    float4 v = *(const float4*)(X + base + row * 64 + c4);
    short4 hv = make_short4(rndbf(v.x), rndbf(v.y), rndbf(v.z), rndbf(v.w));
    *(short4*)(Xh + base + row * 64 + c4) = hv;
    *(short4*)&Sh[row][c4] = hv;
  }
  __syncthreads();

  const size_t tbase = (size_t)bt * 65536 + (size_t)mb * 64;
#pragma unroll
  for (int k = 0; k < 2; ++k) {
    int idx = t + k * 256;
    int d   = idx >> 3;
    int m8  = (idx & 7) * 8;
    bf16x8 hv;
#pragma unroll
    for (int j = 0; j < 8; ++j) hv[j] = Sh[m8 + j][d];
    *(bf16x8*)(XTh + tbase + (size_t)d * 1024 + m8) = hv;
  }
}

// ---------------- pre-pass 2 (v9-verified): A -> bf16 fragment order ------
__global__ __launch_bounds__(256)
void prearr_Abf(const float* __restrict__ A, short* __restrict__ Af)
{
  const int qt  = blockIdx.x >> 5;
  const int gks = blockIdx.x & 31;
  const int kb  = gks * 32;
  const int s   = threadIdx.x;
  short* dst = Af + ((size_t)(qt * 32 + gks) * 2048);

  const int qw = s >> 7;
  const int ln = (s >> 1) & 63;
  const int p  = s & 1;
  const int q  = qt * 64 + qw * 32 + (ln & 31);
  const int h  = ln >> 5;
  const int k0 = kb + 16 * p + 4 * h;
  float4 f0 = *(const float4*)(A + (size_t)q * kN + k0);
  float4 f1 = *(const float4*)(A + (size_t)q * kN + k0 + 8);
  i32x4 u;
  u[0] = (int)pkbf(f0.x, f0.y); u[1] = (int)pkbf(f0.z, f0.w);
  u[2] = (int)pkbf(f1.x, f1.y); u[3] = (int)pkbf(f1.z, f1.w);
  *(i32x4*)(dst + (size_t)qw * 1024 + ln * 16 + p * 8) = u;
}

// ---------------- main fused kernel ----------------
template<int AMODE>
__global__ __launch_bounds__(256)
void sdgcn_v15(const float* __restrict__ X, const float* __restrict__ A,
               const float* __restrict__ W, const float* __restrict__ gamma,
               const float* __restrict__ beta, float* __restrict__ out,
               const short* __restrict__ Xh, const short* __restrict__ XTh,
               const short* __restrict__ Af)
{
  // LDS 38912B, double-buffered padded tiles:
  //   Kh[b][kg] = LB + (b*2+kg)*4608   (32 rows x 72 shorts)
  //   Vt[b][kg] = LB + 18432 + (b*2+kg)*5120 (64 rows x 40 shorts)
  // post-loop union: aM/aZ/aF (1792B @0), Har[64][68] f32 @1792.
  __shared__ __align__(16) unsigned char LB[38912];

  const int t    = threadIdx.x;
  const int wave = t >> 6;
  const int lane = t & 63;
  const int kg   = wave >> 1;
  const int qw   = wave & 1;
  const int half = lane >> 5;
  const int l31  = lane & 31;
  const int bid  = blockIdx.x;
  const int swz  = (bid & 7) * 96 + (bid >> 3);   // XCD-chunked (768 = 8*96)
  const int bt   = swz >> 4;
  const int qt   = swz & 15;
  const int qblk = qt * 64;
  const size_t xb = (size_t)bt * 65536;

  short* Kh0 = (short*)(LB + kg * 4608);
  short* Kh1 = (short*)(LB + 9216 + kg * 4608);
  short* Vt0 = (short*)(LB + 18432 + kg * 5120);
  short* Vt1 = (short*)(LB + 28672 + kg * 5120);
  float* aM  = (float*)LB;             // [2][64]
  float* aZ  = aM + 128;
  float* aF  = aZ + 128;               // [3][64]
  float* Har = (float*)(LB + 1792);    // [64][68]

  // ---- Q B-frags (rounded bf16, hi only)
  const int qmine = qblk + qw * 32 + l31;
  bf16x8 qh[4];
#pragma unroll
  for (int c = 0; c < 4; ++c)
    qh[c] = *(const bf16x8*)(Xh + xb + (size_t)qmine * kD + 16 * c + half * 8);

  f32x16 o0, o1;
#pragma unroll
  for (int r = 0; r < 16; ++r) { o0[r] = 0.f; o1[r] = 0.f; }
  float mrun = -INFINITY, Z = 0.f;

  const int tg = t & 127;

  auto ldK = [&](int kb, int j, bf16x8& h) {
    int ck = tg + 128 * j; int kr = ck >> 3; int kc = (ck & 7) * 8;
    h = *(const bf16x8*)(Xh + xb + (size_t)(kb + kr) * kD + kc);
  };
  auto ldV = [&](int kb, int j, bf16x8& h) {
    int cv = tg + 128 * j; int vd = cv >> 2; int vm = (cv & 3) * 8;
    h = *(const bf16x8*)(XTh + xb + (size_t)vd * 1024 + kb + vm);
  };
  auto stK = [&](short* Kh, int j, bf16x8 h) {
    int ck = tg + 128 * j; int kr = ck >> 3; int kc = (ck & 7) * 8;
    *(bf16x8*)&Kh[kr * 72 + kc] = h;
  };
  auto stV = [&](short* Vt, int j, bf16x8 h) {
    int cv = tg + 128 * j; int vd = cv >> 2; int vm = (cv & 3) * 8;
    *(bf16x8*)&Vt[vd * 40 + vm] = h;
  };

  i32x4 aA = {0,0,0,0}, aB = {0,0,0,0};

  // one k-step: compute tile ks from (Khg, Vtg); prefetch A for ks+1
  auto compute = [&](int ks, const short* Khg, const short* Vtg, bool pfA) {
    const int kb = kg * 512 + ks * 32;

    i32x4 naA = {0,0,0,0}, naB = {0,0,0,0};
    if (AMODE == 1 && pfA) {
      const short* Ab = Af + ((size_t)(qt * 32 + kg * 16 + ks + 1) * 2048)
                           + (size_t)qw * 1024 + (lane << 4);
      naA = *(const i32x4*)(Ab);
      naB = *(const i32x4*)(Ab + 8);
    }

    // A gate: agv[r] = A[qmine][kb + (r&3) + 8*(r>>2) + 4*half]
    float agv[16];
    if (AMODE == 1) {
      unsigned u[8] = {(unsigned)aA[0],(unsigned)aA[1],(unsigned)aA[2],(unsigned)aA[3],
                       (unsigned)aB[0],(unsigned)aB[1],(unsigned)aB[2],(unsigned)aB[3]};
#pragma unroll
      for (int m = 0; m < 8; ++m) {
        agv[2*m]   = __uint_as_float(u[m] << 16);
        agv[2*m+1] = __uint_as_float(u[m] & 0xFFFF0000u);
      }
    } else {
      const float* Arow = A + (size_t)qmine * kN + kb + 4 * half;
      float4 ag0 = *(const float4*)(Arow);
      float4 ag1 = *(const float4*)(Arow + 8);
      float4 ag2 = *(const float4*)(Arow + 16);
      float4 ag3 = *(const float4*)(Arow + 24);
#pragma unroll
      for (int e = 0; e < 4; ++e) {
        agv[e] = ag0[e]; agv[4+e] = ag1[e]; agv[8+e] = ag2[e]; agv[12+e] = ag3[e];
      }
    }

    // ---- QK^T swapped, 1-term: S = Kh.Qh (both RNE-rounded bf16)
    f32x16 sa;
#pragma unroll
    for (int r = 0; r < 16; ++r) sa[r] = 0.f;
    __builtin_amdgcn_s_setprio(1);
#pragma unroll
    for (int c = 0; c < 4; ++c) {
      bf16x8 kh = *(const bf16x8*)&Khg[l31 * 72 + 16 * c + half * 8];
      sa = MFMA32(kh, qh[c], sa);
    }
    __builtin_amdgcn_s_setprio(0);

    // ---- defer-max online softmax (tree max; exp2/fma path)
    float a0 = fmaxf(fmaxf(sa[0],  sa[1]),  sa[2]);
    float a1 = fmaxf(fmaxf(sa[3],  sa[4]),  sa[5]);
    float a2 = fmaxf(fmaxf(sa[6],  sa[7]),  sa[8]);
    float a3 = fmaxf(fmaxf(sa[9],  sa[10]), sa[11]);
    float a4 = fmaxf(fmaxf(sa[12], sa[13]), sa[14]);
    float b0 = fmaxf(fmaxf(a0, a1), a2);
    float sm = fmaxf(fmaxf(b0, fmaxf(a3, a4)), sa[15]);
    sm = fmaxf(sm, __shfl_xor(sm, 32, 64));
    if (__any(sm > mrun + 8.f)) {
      const float nm = fmaxf(mrun, sm);
      const float f  = exp2f((mrun - nm) * kLog2e);   // 0 on first tile
      mrun = nm; Z *= f;
#pragma unroll
      for (int r = 0; r < 16; ++r) {
        const float fr = __shfl(f, (r & 3) + 8 * (r >> 2) + 4 * half, 64);
        o0[r] *= fr; o1[r] *= fr;
      }
    }
    const float mb2 = mrun * kLog2e;
    float pv[16];
#pragma unroll
    for (int r = 0; r < 16; ++r) pv[r] = exp2f(fmaf(sa[r], kLog2e, -mb2));
    float z0 = (pv[0] + pv[1]) + (pv[2] + pv[3]);
    float z1 = (pv[4] + pv[5]) + (pv[6] + pv[7]);
    float z2 = (pv[8] + pv[9]) + (pv[10] + pv[11]);
    float z3 = (pv[12] + pv[13]) + (pv[14] + pv[15]);
    float zt = (z0 + z1) + (z2 + z3);
    zt += __shfl_xor(zt, 32, 64);
    Z += zt;

    float pa[16];
#pragma unroll
    for (int r = 0; r < 16; ++r) pa[r] = pv[r] * agv[r];

    // ---- pack gated P + 4-shuffle cross-half exchange (v13-verified)
    unsigned du[8];
#pragma unroll
    for (int j = 0; j < 8; ++j) du[j] = pkbf(pa[2*j], pa[2*j+1]);
    const bool lo = (half == 0);
    unsigned snd0 = lo ? du[2] : du[0];
    unsigned snd1 = lo ? du[3] : du[1];
    unsigned snd2 = lo ? du[6] : du[4];
    unsigned snd3 = lo ? du[7] : du[5];
    unsigned r0 = (unsigned)__shfl_xor((int)snd0, 32, 64);
    unsigned r1 = (unsigned)__shfl_xor((int)snd1, 32, 64);
    unsigned r2 = (unsigned)__shfl_xor((int)snd2, 32, 64);
    unsigned r3 = (unsigned)__shfl_xor((int)snd3, 32, 64);
    i32x4 w0, w1;
    w0[0] = (int)(lo ? du[0] : r0);
    w0[1] = (int)(lo ? du[1] : r1);
    w0[2] = (int)(lo ? r0 : du[2]);
    w0[3] = (int)(lo ? r1 : du[3]);
    w1[0] = (int)(lo ? du[4] : r2);
    w1[1] = (int)(lo ? du[5] : r3);
    w1[2] = (int)(lo ? r2 : du[6]);
    w1[3] = (int)(lo ? r3 : du[7]);
    bf16x8 pf0 = *(bf16x8*)&w0;
    bf16x8 pf1 = *(bf16x8*)&w1;

    // ---- PV: O[q][d] += P[q][k] V[k][d]
    {
      bf16x8 v0 = *(const bf16x8*)&Vtg[l31 * 40 + half * 8];
      bf16x8 v1 = *(const bf16x8*)&Vtg[l31 * 40 + 16 + half * 8];
      bf16x8 v2 = *(const bf16x8*)&Vtg[(32 + l31) * 40 + half * 8];
      bf16x8 v3 = *(const bf16x8*)&Vtg[(32 + l31) * 40 + 16 + half * 8];
      __builtin_amdgcn_s_setprio(1);
      o0 = MFMA32(pf0, v0, o0);
      o0 = MFMA32(pf1, v1, o0);
      o1 = MFMA32(pf0, v2, o1);
      o1 = MFMA32(pf1, v3, o1);
      __builtin_amdgcn_s_setprio(0);
    }
    aA = naA; aB = naB;
  };

  // ---- prologue: stage tile 0 -> buf0; load A(step 0)
  {
    bf16x8 a0,b0,c0,d0;
    ldK(kg * 512, 0, a0); ldK(kg * 512, 1, b0);
    ldV(kg * 512, 0, c0); ldV(kg * 512, 1, d0);
    stK(Kh0, 0, a0); stK(Kh0, 1, b0); stV(Vt0, 0, c0); stV(Vt0, 1, d0);
  }
  if (AMODE == 1) {
    const short* Ab = Af + ((size_t)(qt * 32 + kg * 16) * 2048)
                         + (size_t)qw * 1024 + (lane << 4);
    aA = *(const i32x4*)(Ab);
    aB = *(const i32x4*)(Ab + 8);
  }
  __syncthreads();

  for (int ks = 0; ks < 16; ks += 2) {
    // phase A: compute ks (buf0); stage ks+1 -> buf1; ONE barrier
    bf16x8 k0,k1,v0,v1;
    ldK(kg * 512 + (ks + 1) * 32, 0, k0);
    ldK(kg * 512 + (ks + 1) * 32, 1, k1);
    ldV(kg * 512 + (ks + 1) * 32, 0, v0);
    ldV(kg * 512 + (ks + 1) * 32, 1, v1);
    compute(ks, Kh0, Vt0, true);
    stK(Kh1, 0, k0); stK(Kh1, 1, k1); stV(Vt1, 0, v0); stV(Vt1, 1, v1);
    __syncthreads();

    // phase B: compute ks+1 (buf1); stage ks+2 -> buf0; ONE barrier
    const bool more = (ks + 2) < 16;
    if (more) {
      ldK(kg * 512 + (ks + 2) * 32, 0, k0);
      ldK(kg * 512 + (ks + 2) * 32, 1, k1);
      ldV(kg * 512 + (ks + 2) * 32, 0, v0);
      ldV(kg * 512 + (ks + 2) * 32, 1, v1);
    }
    compute(ks + 1, Kh1, Vt1, more);
    if (more) {
      stK(Kh0, 0, k0); stK(Kh0, 1, k1); stV(Vt0, 0, v0); stV(Vt0, 1, v1);
    }
    __syncthreads();
  }

  // ================= split-K merge (v5-verified) =================
  if (lane < 32) {
    aM[kg * 64 + qw * 32 + l31] = mrun;
    aZ[kg * 64 + qw * 32 + l31] = Z;
  }
  if (kg == 1) {
#pragma unroll
    for (int r = 0; r < 16; ++r) {
      const int qq = qw * 32 + (r & 3) + 8 * (r >> 2) + 4 * half;
      Har[qq * 68 + l31]      = o0[r];
      Har[qq * 68 + l31 + 32] = o1[r];
    }
  }
  __syncthreads();
  if (kg == 1 && lane < 32) {
    const int q = qw * 32 + l31;
    const float ma = aM[q], mb = mrun;
    const float m  = fmaxf(ma, mb);
    const float fa = __expf(ma - m), fb = __expf(mb - m);
    const float Zs = aZ[q] * fa + Z * fb;
    aF[q]       = fa;
    aF[64 + q]  = fb;
    aF[128 + q] = 1.0f / (8.0f * Zs);   // sqrt(64)=8
  }
  __syncthreads();
  if (kg == 0) {
#pragma unroll
    for (int r = 0; r < 16; ++r) {
      const int qq = qw * 32 + (r & 3) + 8 * (r >> 2) + 4 * half;
      const float fa = aF[qq], fb = aF[64 + qq];
      Har[qq * 68 + l31]      = o0[r] * fa + Har[qq * 68 + l31]      * fb;
      Har[qq * 68 + l31 + 32] = o1[r] * fa + Har[qq * 68 + l31 + 32] * fb;
    }
  }
  __syncthreads();

  // ================= epilogue (v2-verified 16x16 path) =================
  const int g  = lane >> 4;
  const int ql = lane & 15;
  const int er = wave * 16;
  const float i8z = aF[128 + er + ql];

  bf16x8 hh[2], hl[2];
#pragma unroll
  for (int kk = 0; kk < 2; ++kk) {
    const float* hp = &Har[(er + ql) * 68 + kk * 32 + g * 8];
    float4 v0 = *(const float4*)hp;
    float4 v1 = *(const float4*)(hp + 4);
    float v[8] = {v0.x*i8z, v0.y*i8z, v0.z*i8z, v0.w*i8z,
                  v1.x*i8z, v1.y*i8z, v1.z*i8z, v1.w*i8z};
#pragma unroll
    for (int e = 0; e < 8; ++e) { short a, b; splitv(v[e], a, b); hh[kk][e] = a; hl[kk][e] = b; }
  }

  f32x4 lin[4];
#pragma unroll
  for (int c = 0; c < 4; ++c) {
    bf16x8 wh[2], wl[2];
#pragma unroll
    for (int kk = 0; kk < 2; ++kk) {
      const float* wp = W + (size_t)(c * 16 + ql) * kD + kk * 32 + g * 8;
      float4 v0 = *(const float4*)wp;
      float4 v1 = *(const float4*)(wp + 4);
      float v[8] = {v0.x, v0.y, v0.z, v0.w, v1.x, v1.y, v1.z, v1.w};
#pragma unroll
      for (int e = 0; e < 8; ++e) { short a, b; splitv(v[e], a, b); wh[kk][e] = a; wl[kk][e] = b; }
    }
    f32x4 acc = {0.f, 0.f, 0.f, 0.f};
    acc = MFMA16(hh[0], wh[0], acc);
    acc = MFMA16(hh[1], wh[1], acc);
    acc = MFMA16(hh[0], wl[0], acc);
    acc = MFMA16(hh[1], wl[1], acc);
    acc = MFMA16(hl[0], wh[0], acc);
    acc = MFMA16(hl[1], wh[1], acc);
    lin[c] = acc;
  }

  float rl[4][4];
#pragma unroll
  for (int c = 0; c < 4; ++c)
#pragma unroll
    for (int r = 0; r < 4; ++r) rl[c][r] = fmaxf(lin[c][r], 0.f);

  float mu[4], rstd[4];
#pragma unroll
  for (int r = 0; r < 4; ++r) {
    float s1 = rl[0][r] + rl[1][r] + rl[2][r] + rl[3][r];
    float s2 = rl[0][r]*rl[0][r] + rl[1][r]*rl[1][r] + rl[2][r]*rl[2][r] + rl[3][r]*rl[3][r];
#pragma unroll
    for (int off = 1; off < 16; off <<= 1) {
      s1 += __shfl_xor(s1, off, 64);
      s2 += __shfl_xor(s2, off, 64);
    }
    mu[r] = s1 * (1.f / 64.f);
    const float var = s2 * (1.f / 64.f) - mu[r] * mu[r];
    rstd[r] = rsqrtf(var + 1e-5f);
  }

#pragma unroll
  for (int c = 0; c < 4; ++c) {
    const float gm = gamma[c * 16 + ql];
    const float bb = beta[c * 16 + ql];
#pragma unroll
    for (int r = 0; r < 4; ++r) {
      const int qrow = qblk + er + 4 * g + r;
      const size_t off = ((size_t)bt * kN + qrow) * kD + c * 16 + ql;
      out[off] = (rl[c][r] - mu[r]) * rstd[r] * gm + bb + X[off];
    }
  }
}

extern "C" void kernel_launch(void* const* d_in, const int* in_sizes, int n_in,
                              void* d_out, int out_size, void* d_ws, size_t ws_size,
                              hipStream_t stream) {
  const float* X     = (const float*)d_in[0];
  const float* A     = (const float*)d_in[1];
  const float* W     = (const float*)d_in[2];
  const float* gamma = (const float*)d_in[3];
  const float* beta  = (const float*)d_in[4];
  float* out = (float*)d_out;

  short* Xh  = (short*)d_ws;
  short* XTh = Xh  + kPlane;
  short* Af  = XTh + kPlane;

  const size_t need = (2 * kPlane + kAfShorts) * sizeof(short);

  presplit<<<dim3(48 * 16), 256, 0, stream>>>(X, Xh, XTh);
  if (ws_size >= need) {
    prearr_Abf<<<dim3(16 * 32), 256, 0, stream>>>(A, Af);
    sdgcn_v15<1><<<dim3(48 * 16), 256, 0, stream>>>(X, A, W, gamma, beta, out,
                                                    Xh, XTh, Af);
  } else {
    sdgcn_v15<0><<<dim3(48 * 16), 256, 0, stream>>>(X, A, W, gamma, beta, out,
                                                    Xh, XTh, Af);
  }
}